// Round 11
// baseline (590.986 us; speedup 1.0000x reference)
//
#include <hip/hip_runtime.h>
#include <hip/hip_cooperative_groups.h>

#define EPS 1e-5f
#define CAP 128           // slots per dst (deg ~ Poisson(32); P(>=128) ~ 1e-40)
#define DR  128           // dsts per coarse bucket
#define NB  391           // ceil(50000/128) coarse buckets
#define CB  4608          // pairs per coarse bucket (mean 4096, +8 sigma)
#define GS  16            // gcur padding: 16 ints = 64B line per bucket
#define CHUNK 4096        // edges per phase-1 work block

typedef __attribute__((ext_vector_type(8))) short bf16x8;
typedef __attribute__((ext_vector_type(4))) float f32x4;

// branchless RNE fp32->bf16 (identical to __float2bfloat16 for finite inputs; pure int ops)
__device__ __forceinline__ unsigned int f2bf(float f) {
  union { float f; unsigned int u; } v; v.f = f;
  return (v.u + 0x7fffu + ((v.u >> 16) & 1u)) >> 16;
}
__device__ __forceinline__ float bf2f_lo(unsigned int u) {
  union { unsigned int i; float f; } v; v.i = u << 16; return v.f;
}
__device__ __forceinline__ float bf2f_hi(unsigned int u) {
  union { unsigned int i; float f; } v; v.i = u & 0xffff0000u; return v.f;
}

struct Params {
  const int *esrc, *edst;
  const float4* x;
  const float *W1, *b1, *g0, *be0, *m0, *v0, *g1, *be1, *m1, *v1, *W2, *b2;
  int* gcur; unsigned int* coarse; unsigned short* slot; int* wcnt; float* dinv;
  unsigned short* Wb; float *c1, *s1, *u1, *xs2;
  unsigned short *Xb, *xsb;
  float* out;
  int n, e, npad, nbp1;
};

// ONE cooperative kernel: P0 zero | P1 cvtx||p1||prep | P2 p2||gemm | P3 scale | P4 gather1 | P5 gather2
// LDS 33.8KB, launch_bounds(256,4): 4 blocks/CU (VGPR<=128) -> 1024 co-resident blocks.
__global__ __launch_bounds__(256, 4) void k_fused(Params P) {
  namespace cg = cooperative_groups;
  cg::grid_group grid = cg::this_grid();
  __shared__ int SM[8448];   // 33792 B: p1 hist/base/loff | prep s0/t0 | p2 lcnt/nqr/lslot
  const int tid = threadIdx.x;
  const int nblk = gridDim.x;
  const int gtid = blockIdx.x * 256 + tid;
  const int gstride = nblk * 256;

  // ---- P0: zero gcur ----
  for (int i = gtid; i < NB * GS; i += gstride) P.gcur[i] = 0;
  grid.sync();

  // ---- P1: cvtx (flat) then p1 (391 chunks) + prep (1) ----
  {
    int n4 = P.n * 32, npad4 = P.npad * 32;     // uint2 count in Xb
    for (int i = gtid; i < npad4; i += gstride) {
      uint2 o = make_uint2(0u, 0u);
      if (i < n4) {
        float4 v = P.x[i];
        o.x = (f2bf(v.y) << 16) | f2bf(v.x);
        o.y = (f2bf(v.w) << 16) | f2bf(v.z);
      }
      ((uint2*)P.Xb)[i] = o;
    }
    for (int wb = blockIdx.x; wb < P.nbp1 + 1; wb += nblk) {
      if (wb < P.nbp1) {
        // p1: coarse-bin edges, packed 4B entries ((d&127)<<16 | src); src < 2^16
        int* hist = SM; int* base = SM + NB; int* loff = SM + 2 * NB;
        for (int i = tid; i < NB; i += 256) { hist[i] = 0; loff[i] = 0; }
        __syncthreads();
        int e0 = wb * CHUNK, e1 = min(e0 + CHUNK, P.e);
        for (int i = e0 + tid; i < e1; i += 256) atomicAdd(&hist[P.edst[i] >> 7], 1);
        __syncthreads();
        int rot = wb % NB;                      // de-lockstep cursor-line reservations
        for (int bb = tid; bb < NB; bb += 256) {
          int b = bb + rot; if (b >= NB) b -= NB;
          int h = hist[b];
          if (h > 0) base[b] = atomicAdd(&P.gcur[b * GS], h);
        }
        __syncthreads();
        for (int i = e0 + tid; i < e1; i += 256) {
          int d = P.edst[i], s = P.esrc[i];
          int b = d >> 7;
          int p = base[b] + atomicAdd(&loff[b], 1);
          if (p < CB) P.coarse[(size_t)b * CB + p] = ((unsigned)(d & 127) << 16) | (unsigned)s;
        }
      } else {
        // prep: BN folds, swizzled bf16 Wb, c1/s1/u1, pad entries
        float* s0s = (float*)SM; float* t0s = s0s + 128;
        if (tid < 128) {
          float s0 = P.g0[tid] * rsqrtf(P.v0[tid] + EPS);
          s0s[tid] = s0;
          t0s[tid] = P.be0[tid] - P.m0[tid] * s0;
          float s = P.g1[tid] * rsqrtf(P.v1[tid] + EPS);
          P.s1[tid] = s;
          P.u1[tid] = fmaf(P.b1[tid] - P.m1[tid], s, P.be1[tid]);
        }
        __syncthreads();
        if (tid < 128) {
          float acc = 0.f;
          for (int k = 0; k < 128; ++k) acc = fmaf(t0s[k], P.W1[k * 128 + tid], acc);
          P.c1[tid] = acc;
        }
        if (tid == 0) P.dinv[P.n] = 0.f;
        if (tid < 16) ((uint4*)P.xsb)[(size_t)P.n * 16 + tid] = make_uint4(0, 0, 0, 0);
        // Wb[((c*8+t)*64+l)*8+j] = bf16(s0[k]*W1[k][col]); k=c*32+(l>>4)*8+j, col=t*16+(l&15)
        for (int idx = tid; idx < 16384; idx += 256) {
          int k = idx >> 7, col = idx & 127;
          float w = P.W1[idx] * s0s[k];
          int c = k >> 5, j = k & 7, lq2 = (k >> 3) & 3;
          int t = col >> 4, li = col & 15;
          P.Wb[(((c * 8 + t) * 64) + lq2 * 16 + li) * 8 + j] = (unsigned short)f2bf(w);
        }
      }
      __syncthreads();
    }
  }
  grid.sync();

  // ---- P2: p2 (NB buckets) | gemm1m (npad/64 blocks), xsb UNSCALED ----
  {
    int ngemm = P.npad / 64;
    for (int wb = blockIdx.x; wb < NB + ngemm; wb += nblk) {
      if (wb < NB) {
        int* lcnt = SM; int* nqr = SM + 128;
        unsigned short* lslot = (unsigned short*)(SM + 256);   // 32 KB
        for (int i = tid; i < DR; i += 256) lcnt[i] = 0;
        unsigned pad2 = ((unsigned)P.n << 16) | (unsigned)P.n;
        for (int q = tid; q < DR * CAP / 2; q += 256) ((unsigned*)lslot)[q] = pad2;
        __syncthreads();
        int cb = wb;
        int cnt = P.gcur[cb * GS]; if (cnt > CB) cnt = CB;
        const unsigned* src = P.coarse + (size_t)cb * CB;
        for (int i = tid; i < cnt; i += 256) {
          unsigned v = src[i];
          int ld = (int)(v >> 16);
          int pos = atomicAdd(&lcnt[ld], 1);
          if (pos < CAP) lslot[ld * CAP + pos] = (unsigned short)(v & 0xffffu);
        }
        __syncthreads();
        int dbase = cb * DR;
        for (int ld = tid; ld < DR; ld += 256) {
          int c = min(lcnt[ld], CAP);
          nqr[ld] = ((((c + 3) >> 2) + 3) & ~3);   // quads rounded to x4 (4-deep gather)
          int d = dbase + ld;
          if (d < P.n) { P.wcnt[d] = c; P.dinv[d] = rsqrtf((float)c + 1.0f); }
        }
        __syncthreads();
        const uint2* ls8 = (const uint2*)lslot;
        uint2* s8 = (uint2*)P.slot;
        for (int idx = tid; idx < DR * 32; idx += 256) {
          int ld = idx >> 5, qi = idx & 31;
          if (qi < nqr[ld] && dbase + ld < P.n) s8[(size_t)cb * (DR * 32) + idx] = ls8[idx];
        }
      } else {
        // gemm1m MFMA bf16, no LDS: xsb = bf16(Xb @ W + c1)
        // A[m=lane&15][k=(lane>>4)*8+j]; D: col=lane&15, row=(lane>>4)*4+reg (verified)
        int gb = wb - NB;
        const int wave = tid >> 6, lane = tid & 63;
        int r0 = gb * 64 + wave * 16;
        int lr = lane & 15, lq = lane >> 4;
        const bf16x8* a_base = (const bf16x8*)(P.Xb + (size_t)(r0 + lr) * 128);
        const bf16x8* wbp = (const bf16x8*)P.Wb;
        f32x4 acc[8];
#pragma unroll
        for (int t = 0; t < 8; ++t) acc[t] = (f32x4){0.f, 0.f, 0.f, 0.f};
#pragma unroll
        for (int c = 0; c < 4; ++c) {
          bf16x8 a = a_base[c * 4 + lq];
#pragma unroll
          for (int t = 0; t < 8; ++t) {
            bf16x8 b = wbp[(c * 8 + t) * 64 + lane];
            acc[t] = __builtin_amdgcn_mfma_f32_16x16x32_bf16(a, b, acc[t], 0, 0, 0);
          }
        }
#pragma unroll
        for (int reg = 0; reg < 4; ++reg) {
          int row = r0 + lq * 4 + reg;
          if (row < P.n) {
            unsigned short* orow = P.xsb + (size_t)row * 128 + lr;
#pragma unroll
            for (int t = 0; t < 8; ++t) {
              float v = acc[t][reg] + P.c1[t * 16 + lr];
              orow[t * 16] = (unsigned short)f2bf(v);
            }
          }
        }
      }
      __syncthreads();
    }
  }
  grid.sync();

  // ---- P3: scale xsb rows in place by dinv[row] (restores pre-scaled gather) ----
  {
    uint4* xb4 = (uint4*)P.xsb;
    int total = P.n * 16;                     // 16 uint4 per 256B row
    for (int i = gtid; i < total; i += gstride) {
      float dd = P.dinv[i >> 4];
      uint4 v = xb4[i];
      v.x = (f2bf(bf2f_hi(v.x) * dd) << 16) | f2bf(bf2f_lo(v.x) * dd);
      v.y = (f2bf(bf2f_hi(v.y) * dd) << 16) | f2bf(bf2f_lo(v.y) * dd);
      v.z = (f2bf(bf2f_hi(v.z) * dd) << 16) | f2bf(bf2f_lo(v.z) * dd);
      v.w = (f2bf(bf2f_hi(v.w) * dd) << 16) | f2bf(bf2f_lo(v.w) * dd);
      xb4[i] = v;
    }
  }
  grid.sync();

  // ---- P4: gather1 fused BN1+ReLU+GEMM2 (pre-scaled xsb; R9 body, wave per dst) ----
  {
    const int wave = tid >> 6, lane = tid & 63;
    const int sub = lane >> 4, cl = lane & 15;
    const uint4* xs4 = (const uint4*)P.xsb;
    float4 sA = ((const float4*)P.s1)[cl * 2], sB = ((const float4*)P.s1)[cl * 2 + 1];
    float4 uA = ((const float4*)P.u1)[cl * 2], uB = ((const float4*)P.u1)[cl * 2 + 1];
    float4 wA = ((const float4*)P.W2)[cl * 4 + 0];
    float4 wB = ((const float4*)P.W2)[cl * 4 + 1];
    float4 wC = ((const float4*)P.W2)[cl * 4 + 2];
    float4 wD = ((const float4*)P.W2)[cl * 4 + 3];
    int nwaves = nblk * 4;
    for (int d = blockIdx.x * 4 + wave; d < P.n; d += nwaves) {
      int cnt = P.wcnt[d];
      int nq4 = ((((cnt + 3) >> 2) + 3) & ~3);   // matches p2; pads -> zero row
      const unsigned short* slotd = P.slot + ((size_t)d << 7);
      float a0 = 0.f, a1 = 0.f, a2 = 0.f, a3 = 0.f, a4 = 0.f, a5 = 0.f, a6 = 0.f, a7 = 0.f;
#define ACC(R) { a0 += bf2f_lo(R.x); a1 += bf2f_hi(R.x); a2 += bf2f_lo(R.y); a3 += bf2f_hi(R.y); \
                 a4 += bf2f_lo(R.z); a5 += bf2f_hi(R.z); a6 += bf2f_lo(R.w); a7 += bf2f_hi(R.w); }
      for (int q = 0; q < nq4; q += 4) {        // 4 quad-loads (4KB) in flight, no tail
        int i0 = slotd[(q + 0) * 4 + sub];
        int i1 = slotd[(q + 1) * 4 + sub];
        int i2 = slotd[(q + 2) * 4 + sub];
        int i3 = slotd[(q + 3) * 4 + sub];
        uint4 r0 = xs4[(size_t)i0 * 16 + cl];
        uint4 r1 = xs4[(size_t)i1 * 16 + cl];
        uint4 r2 = xs4[(size_t)i2 * 16 + cl];
        uint4 r3 = xs4[(size_t)i3 * 16 + cl];
        ACC(r0); ACC(r1); ACC(r2); ACC(r3);
      }
#define FOLD(OFF) { a0 += __shfl_xor(a0, OFF); a1 += __shfl_xor(a1, OFF); \
                    a2 += __shfl_xor(a2, OFF); a3 += __shfl_xor(a3, OFF); \
                    a4 += __shfl_xor(a4, OFF); a5 += __shfl_xor(a5, OFF); \
                    a6 += __shfl_xor(a6, OFF); a7 += __shfl_xor(a7, OFF); }
      FOLD(16); FOLD(32);
      uint4 sr = xs4[(size_t)d * 16 + cl];      // self-loop row (pre-scaled), once after fold
      ACC(sr);
#undef ACC
#undef FOLD
      float dd = P.dinv[d];
      float h0 = fmaxf(fmaf(a0 * dd, sA.x, uA.x), 0.f);
      float h1 = fmaxf(fmaf(a1 * dd, sA.y, uA.y), 0.f);
      float h2 = fmaxf(fmaf(a2 * dd, sA.z, uA.z), 0.f);
      float h3 = fmaxf(fmaf(a3 * dd, sA.w, uA.w), 0.f);
      float h4 = fmaxf(fmaf(a4 * dd, sB.x, uB.x), 0.f);
      float h5 = fmaxf(fmaf(a5 * dd, sB.y, uB.y), 0.f);
      float h6 = fmaxf(fmaf(a6 * dd, sB.z, uB.z), 0.f);
      float h7 = fmaxf(fmaf(a7 * dd, sB.w, uB.w), 0.f);
      float p0 = h0 * wA.x + h1 * wA.z + h2 * wB.x + h3 * wB.z
               + h4 * wC.x + h5 * wC.z + h6 * wD.x + h7 * wD.z;
      float p1 = h0 * wA.y + h1 * wA.w + h2 * wB.y + h3 * wB.w
               + h4 * wC.y + h5 * wC.w + h6 * wD.y + h7 * wD.w;
      for (int off = 1; off < 16; off <<= 1) {
        p0 += __shfl_xor(p0, off);
        p1 += __shfl_xor(p1, off);
      }
      if (lane == 0) ((float2*)P.xs2)[d] = make_float2(p0 * dd, p1 * dd);
    }
  }
  grid.sync();

  // ---- P5: gather2: out[d] = b2 + dinv[d]*(xs2[d] + sum xs2[src]) ----
  {
    const int wave = tid >> 6, lane = tid & 63;
    float b20 = P.b2[0], b21 = P.b2[1];
    int nwaves = nblk * 4;
    for (int d = blockIdx.x * 4 + wave; d < P.n; d += nwaves) {
      int cnt = P.wcnt[d];
      const unsigned short* slotd = P.slot + ((size_t)d << 7);
      float p0 = 0.f, p1 = 0.f;
      for (int k = lane; k < cnt; k += 64) {
        int s = slotd[k];
        float2 v = ((const float2*)P.xs2)[s];
        p0 += v.x; p1 += v.y;
      }
      for (int off = 32; off > 0; off >>= 1) {
        p0 += __shfl_down(p0, off);
        p1 += __shfl_down(p1, off);
      }
      if (lane == 0) {
        float dd = P.dinv[d];
        float2 self = ((const float2*)P.xs2)[d];
        P.out[d * 2 + 0] = fmaf(dd, p0 + self.x, b20);
        P.out[d * 2 + 1] = fmaf(dd, p1 + self.y, b21);
      }
    }
  }
}

extern "C" void kernel_launch(void* const* d_in, const int* in_sizes, int n_in,
                              void* d_out, int out_size, void* d_ws, size_t ws_size,
                              hipStream_t stream) {
  const int n = in_sizes[0] / 128;   // 50000 < 2^16: node ids fit in ushort
  const int e = in_sizes[1] / 2;
  const int npad = ((n + 63) / 64) * 64;

  // workspace layout (16B-aligned; n=50000) — ~46.5 MB
  int*            gcur   = (int*)d_ws;                             // 6272 ints
  unsigned int*   coarse = (unsigned int*)(gcur + 6272);           // NB*CB uint (7.2 MB)
  unsigned short* slot   = (unsigned short*)(coarse + (size_t)NB * CB);  // n*CAP ushort (12.8 MB)
  int*            wcnt   = (int*)(slot + (size_t)n * CAP);         // n
  float*          dinv   = (float*)(wcnt + n);                     // n+1 (dinv[n]=0)
  unsigned short* Wb     = (unsigned short*)(dinv + n + 4);        // 16384 bf16 (32 KB)
  float*          c1     = (float*)(Wb + 16384);                   // 128
  float*          s1     = c1 + 128;                               // 128
  float*          u1     = s1 + 128;                               // 128
  float*          xs2    = u1 + 128;                               // n*2
  unsigned short* Xb     = (unsigned short*)(xs2 + (size_t)n * 2); // npad*128 bf16 (12.8 MB)
  unsigned short* xsb    = Xb + (size_t)npad * 128;                // (n+1)*128 bf16 (12.8 MB)

  Params prm;
  prm.esrc = (const int*)d_in[1];
  prm.edst = ((const int*)d_in[1]) + e;
  prm.x   = (const float4*)d_in[0];
  prm.W1  = (const float*)d_in[6];  prm.b1  = (const float*)d_in[7];
  prm.g0  = (const float*)d_in[2];  prm.be0 = (const float*)d_in[3];
  prm.m0  = (const float*)d_in[4];  prm.v0  = (const float*)d_in[5];
  prm.g1  = (const float*)d_in[8];  prm.be1 = (const float*)d_in[9];
  prm.m1  = (const float*)d_in[10]; prm.v1  = (const float*)d_in[11];
  prm.W2  = (const float*)d_in[12]; prm.b2  = (const float*)d_in[13];
  prm.gcur = gcur; prm.coarse = coarse; prm.slot = slot; prm.wcnt = wcnt; prm.dinv = dinv;
  prm.Wb = Wb; prm.c1 = c1; prm.s1 = s1; prm.u1 = u1; prm.xs2 = xs2;
  prm.Xb = Xb; prm.xsb = xsb;
  prm.out = (float*)d_out;
  prm.n = n; prm.e = e; prm.npad = npad;
  prm.nbp1 = (e + CHUNK - 1) / CHUNK;

  // cooperative grid must be fully co-resident: occupancy-query-sized
  int nbPerCU = 0;
  (void)hipOccupancyMaxActiveBlocksPerMultiprocessor(&nbPerCU, k_fused, 256, 0);
  if (nbPerCU < 1) nbPerCU = 1;
  int dev = 0, cus = 0;
  (void)hipGetDevice(&dev);
  (void)hipDeviceGetAttribute(&cus, hipDeviceAttributeMultiprocessorCount, dev);
  if (cus <= 0) cus = 256;
  long long nblocks = (long long)nbPerCU * cus;
  if (nblocks > 2048) nblocks = 2048;
  if (nblocks < 64) nblocks = 64;

  void* args[] = { (void*)&prm };
  (void)hipLaunchCooperativeKernel((const void*)k_fused, dim3((unsigned)nblocks), dim3(256),
                                   args, 0, stream);
}

// Round 12
// 255.633 us; speedup vs baseline: 2.3119x; 2.3119x over previous
//
#include <hip/hip_runtime.h>

#define EPS 1e-5f
#define CAP 128           // slots per dst (deg ~ Poisson(32); P(>=128) ~ 1e-40)
#define DR  128           // dsts per coarse bucket
#define NB  391           // ceil(50000/128) coarse buckets
#define CB  4608          // pairs per coarse bucket (mean 4096, +8 sigma)
#define GS  16            // gcur padding: 16 ints = 64B line per bucket
#define CS  32            // cntp padding: 32 ints = 128B line per dst counter
#define CHUNK 4096        // edges per phase-1 work block

typedef __attribute__((ext_vector_type(8))) short bf16x8;
typedef __attribute__((ext_vector_type(4))) float f32x4;

// branchless RNE fp32->bf16 (identical to __float2bfloat16 for finite inputs; pure int ops)
__device__ __forceinline__ unsigned int f2bf(float f) {
  union { float f; unsigned int u; } v; v.f = f;
  return (v.u + 0x7fffu + ((v.u >> 16) & 1u)) >> 16;
}
__device__ __forceinline__ float bf2f_lo(unsigned int u) {
  union { unsigned int i; float f; } v; v.i = u << 16; return v.f;
}
__device__ __forceinline__ float bf2f_hi(unsigned int u) {
  union { unsigned int i; float f; } v; v.i = u & 0xffff0000u; return v.f;
}

// ================= Kernel A: p1+count (blocks [0,nbp1)) | prep (block nbp1) | cvtx (rest) ====
// gcur and cntp pre-zeroed by ONE hipMemsetAsync (contiguous).
// Degree counts via fire-and-forget global atomics on 128B-padded counters, fused into p1's
// histogram loop (R4 lesson: padded-counter atomics are cheap; partial-line scatters are not).
__global__ __launch_bounds__(256) void k_A(
    const int* __restrict__ esrc, const int* __restrict__ edst,
    int* __restrict__ gcur, int* __restrict__ cntp,
    unsigned int* __restrict__ coarse, int e, int nb_p1,
    const float* __restrict__ W1, const float* __restrict__ b1,
    const float* __restrict__ g0, const float* __restrict__ be0,
    const float* __restrict__ m0, const float* __restrict__ v0,
    const float* __restrict__ g1, const float* __restrict__ be1,
    const float* __restrict__ m1, const float* __restrict__ v1,
    const float4* __restrict__ x,
    unsigned short* __restrict__ Wb, float* __restrict__ c1,
    float* __restrict__ s1, float* __restrict__ u1,
    unsigned short* __restrict__ xsb,
    uint2* __restrict__ Xb4, int n, int n4, int npad4) {
  __shared__ int hist[NB];
  __shared__ int base[NB];
  __shared__ int loff[NB];
  __shared__ float s0s[128], t0s[128];
  const int tid = threadIdx.x;
  int bid = blockIdx.x;
  if (bid < nb_p1) {
    // ---- p1: coarse-bin edges, packed 4B entries ((d&127)<<16 | src); + degree atomics ----
    for (int i = tid; i < NB; i += 256) { hist[i] = 0; loff[i] = 0; }
    __syncthreads();
    int e0 = bid * CHUNK;
    int e1 = min(e0 + CHUNK, e);
    for (int i = e0 + tid; i < e1; i += 256) {
      int d = edst[i];
      atomicAdd(&hist[d >> 7], 1);
      atomicAdd(&cntp[d << 5], 1);            // fire-and-forget; 1 line per dst
    }
    __syncthreads();
    int rot = bid % NB;     // rotate reservation order: avoid cursor-line lockstep
    for (int bb = tid; bb < NB; bb += 256) {
      int b = bb + rot; if (b >= NB) b -= NB;
      int h = hist[b];
      if (h > 0) base[b] = atomicAdd(&gcur[b * GS], h);
    }
    __syncthreads();
    for (int i = e0 + tid; i < e1; i += 256) {
      int d = edst[i], s = esrc[i];
      int b = d >> 7;
      int p = base[b] + atomicAdd(&loff[b], 1);
      if (p < CB) coarse[(size_t)b * CB + p] = ((unsigned int)(d & 127) << 16) | (unsigned int)s;
    }
    return;
  }
  if (bid == nb_p1) {
    // ---- prep: BN folds, swizzled bf16 Wb, c1/s1/u1, zero xsb pad row ----
    if (tid < 128) {
      float s0 = g0[tid] * rsqrtf(v0[tid] + EPS);
      s0s[tid] = s0;
      t0s[tid] = be0[tid] - m0[tid] * s0;
      float s = g1[tid] * rsqrtf(v1[tid] + EPS);
      s1[tid] = s;
      u1[tid] = fmaf(b1[tid] - m1[tid], s, be1[tid]);  // h = relu(agg*s1 + u1)
    }
    __syncthreads();
    if (tid < 128) {
      float acc = 0.f;
      for (int k = 0; k < 128; ++k) acc = fmaf(t0s[k], W1[k * 128 + tid], acc);
      c1[tid] = acc;
    }
    if (tid < 16) ((uint4*)xsb)[(size_t)n * 16 + tid] = make_uint4(0, 0, 0, 0);  // pad row
    // Wb[((c*8+t)*64 + l)*8 + j] = bf16(s0[k]*W1[k][col]); k=c*32+(l>>4)*8+j, col=t*16+(l&15)
    for (int idx = tid; idx < 16384; idx += 256) {
      int k = idx >> 7, col = idx & 127;
      float w = W1[idx] * s0s[k];
      int c = k >> 5, j = k & 7, lq2 = (k >> 3) & 3;
      int t = col >> 4, li = col & 15;
      Wb[(((c * 8 + t) * 64) + lq2 * 16 + li) * 8 + j] = (unsigned short)f2bf(w);
    }
    return;
  }
  // ---- cvtx: Xb = bf16(x), rows >= n zero (pad to npad) ----
  int i = (bid - nb_p1 - 1) * 256 + tid;
  if (i >= npad4) return;
  uint2 o = make_uint2(0u, 0u);
  if (i < n4) {
    float4 v = x[i];
    o.x = (f2bf(v.y) << 16) | f2bf(v.x);
    o.y = (f2bf(v.w) << 16) | f2bf(v.z);
  }
  Xb4[i] = o;
}

// ================= Kernel B: p2 (blocks [0,NB)) | gemm1m scaled (rest) =======================
// gemm reads its row's degree straight from cntp (complete after A) -> xsb is PRE-SCALED,
// restoring the R9 gather1 body. p2 and gemm remain concurrent.
__global__ __launch_bounds__(256) void k_B(
    const int* __restrict__ gcur, const int* __restrict__ cntp,
    const unsigned int* __restrict__ coarse,
    unsigned short* __restrict__ slot, int* __restrict__ wcnt, float* __restrict__ dinv,
    const unsigned short* __restrict__ Xb, const unsigned short* __restrict__ Wb,
    const float* __restrict__ c1, unsigned short* __restrict__ xsb, int n) {
  __shared__ int lcnt[DR];
  __shared__ int nqr[DR];
  __shared__ unsigned short lslot[DR * CAP];   // 32 KB
  const int tid = threadIdx.x;
  if (blockIdx.x < NB) {
    // ---- p2: LDS fine-bin one coarse bucket -> ushort slot quads + wcnt + dinv ----
    for (int i = tid; i < DR; i += 256) lcnt[i] = 0;
    unsigned int padpat = ((unsigned int)n << 16) | (unsigned int)n;
    for (int q = tid; q < DR * CAP / 2; q += 256) ((unsigned int*)lslot)[q] = padpat;
    __syncthreads();
    int cb = blockIdx.x;
    int cnt = gcur[cb * GS]; if (cnt > CB) cnt = CB;
    const unsigned int* src = coarse + (size_t)cb * CB;
    for (int i = tid; i < cnt; i += 256) {
      unsigned int v = src[i];
      int ld = (int)(v >> 16);
      int pos = atomicAdd(&lcnt[ld], 1);
      if (pos < CAP) lslot[ld * CAP + pos] = (unsigned short)(v & 0xffffu);
    }
    __syncthreads();
    int dbase = cb * DR;
    for (int ld = tid; ld < DR; ld += 256) {
      int c = min(lcnt[ld], CAP);
      nqr[ld] = ((((c + 3) >> 2) + 3) & ~3);   // quads rounded to x4 for the 4-deep gather
      int d = dbase + ld;
      if (d < n) {
        wcnt[d] = c;
        dinv[d] = rsqrtf((float)c + 1.0f);
      }
    }
    __syncthreads();
    const uint2* ls8 = (const uint2*)lslot;    // 8 B = one quad of 4 ushort slots
    uint2* s8 = (uint2*)slot;
    for (int idx = tid; idx < DR * 32; idx += 256) {
      int ld = idx >> 5, qi = idx & 31;
      if (qi < nqr[ld] && dbase + ld < n) s8[(size_t)cb * (DR * 32) + idx] = ls8[idx];
    }
    return;
  }
  // ---- gemm1m (MFMA bf16, no LDS): xsb = bf16((Xb @ W + c1) * dinv[row]) ----
  // dinv[row] = rsqrt(min(cntp[row],CAP)+1), counts complete after kernel A.
  // A[m=lane&15][k=(lane>>4)*8+j]; D: col=lane&15, row=(lane>>4)*4+reg (verified layouts).
  const int gb = blockIdx.x - NB;
  const int wave = tid >> 6, lane = tid & 63;
  const int r0 = gb * 64 + wave * 16;
  const int lr = lane & 15, lq = lane >> 4;
  const bf16x8* a_base = (const bf16x8*)(Xb + (size_t)(r0 + lr) * 128);  // 16 units/row
  const bf16x8* wb = (const bf16x8*)Wb;
  f32x4 acc[8];
#pragma unroll
  for (int t = 0; t < 8; ++t) acc[t] = (f32x4){0.f, 0.f, 0.f, 0.f};
#pragma unroll
  for (int c = 0; c < 4; ++c) {
    bf16x8 a = a_base[c * 4 + lq];
#pragma unroll
    for (int t = 0; t < 8; ++t) {
      bf16x8 b = wb[(c * 8 + t) * 64 + lane];
      acc[t] = __builtin_amdgcn_mfma_f32_16x16x32_bf16(a, b, acc[t], 0, 0, 0);
    }
  }
#pragma unroll
  for (int reg = 0; reg < 4; ++reg) {
    int row = r0 + lq * 4 + reg;
    if (row < n) {
      float dd = rsqrtf((float)min(cntp[row << 5], CAP) + 1.0f);
      unsigned short* orow = xsb + (size_t)row * 128 + lr;
#pragma unroll
      for (int t = 0; t < 8; ++t) {
        float v = (acc[t][reg] + c1[t * 16 + lr]) * dd;
        orow[t * 16] = (unsigned short)f2bf(v);
      }
    }
  }
}

// ---------- gather1 fused BN1+ReLU+GEMM2 (R9 body): wave per dst, 4 quad-loads in flight ----
// xsb rows pre-scaled by dinv[src]; lane = 16*sub + cl.
__global__ __launch_bounds__(256) void k_gather1(const int* __restrict__ wcnt,
                                                 const unsigned short* __restrict__ slot,
                                                 const uint4* __restrict__ xs4,
                                                 const float* __restrict__ dinv,
                                                 const float* __restrict__ s1,
                                                 const float* __restrict__ u1,
                                                 const float* __restrict__ W2,
                                                 float* __restrict__ xs2, int n) {
  int wave = threadIdx.x >> 6, lane = threadIdx.x & 63;
  int d = blockIdx.x * 4 + wave;
  if (d >= n) return;
  int sub = lane >> 4, cl = lane & 15;
  int cnt = wcnt[d];
  int nq4 = ((((cnt + 3) >> 2) + 3) & ~3);  // matches k_p2 rounding; pads -> zero row
  const unsigned short* slotd = slot + ((size_t)d << 7);
  float a0 = 0.f, a1 = 0.f, a2 = 0.f, a3 = 0.f, a4 = 0.f, a5 = 0.f, a6 = 0.f, a7 = 0.f;
#define ACC(R) { a0 += bf2f_lo(R.x); a1 += bf2f_hi(R.x); a2 += bf2f_lo(R.y); a3 += bf2f_hi(R.y); \
                 a4 += bf2f_lo(R.z); a5 += bf2f_hi(R.z); a6 += bf2f_lo(R.w); a7 += bf2f_hi(R.w); }
  for (int q = 0; q < nq4; q += 4) {        // 4 quad-loads (4KB) in flight, no tail
    int i0 = slotd[(q + 0) * 4 + sub];
    int i1 = slotd[(q + 1) * 4 + sub];
    int i2 = slotd[(q + 2) * 4 + sub];
    int i3 = slotd[(q + 3) * 4 + sub];
    uint4 r0 = xs4[(size_t)i0 * 16 + cl];
    uint4 r1 = xs4[(size_t)i1 * 16 + cl];
    uint4 r2 = xs4[(size_t)i2 * 16 + cl];
    uint4 r3 = xs4[(size_t)i3 * 16 + cl];
    ACC(r0); ACC(r1); ACC(r2); ACC(r3);
  }
  // fold the 4 edge-subgroups (xor 16, 32) -> every lane holds full channel sums
#define FOLD(OFF) { a0 += __shfl_xor(a0, OFF); a1 += __shfl_xor(a1, OFF); \
                    a2 += __shfl_xor(a2, OFF); a3 += __shfl_xor(a3, OFF); \
                    a4 += __shfl_xor(a4, OFF); a5 += __shfl_xor(a5, OFF); \
                    a6 += __shfl_xor(a6, OFF); a7 += __shfl_xor(a7, OFF); }
  FOLD(16); FOLD(32);
  uint4 sr = xs4[(size_t)d * 16 + cl];  // self-loop row (pre-scaled), added once after fold
  ACC(sr);
#undef ACC
#undef FOLD
  float dd = dinv[d];
  float4 sA = ((const float4*)s1)[cl * 2], sB = ((const float4*)s1)[cl * 2 + 1];
  float4 uA = ((const float4*)u1)[cl * 2], uB = ((const float4*)u1)[cl * 2 + 1];
  float h0 = fmaxf(fmaf(a0 * dd, sA.x, uA.x), 0.f);
  float h1 = fmaxf(fmaf(a1 * dd, sA.y, uA.y), 0.f);
  float h2 = fmaxf(fmaf(a2 * dd, sA.z, uA.z), 0.f);
  float h3 = fmaxf(fmaf(a3 * dd, sA.w, uA.w), 0.f);
  float h4 = fmaxf(fmaf(a4 * dd, sB.x, uB.x), 0.f);
  float h5 = fmaxf(fmaf(a5 * dd, sB.y, uB.y), 0.f);
  float h6 = fmaxf(fmaf(a6 * dd, sB.z, uB.z), 0.f);
  float h7 = fmaxf(fmaf(a7 * dd, sB.w, uB.w), 0.f);
  // W2 rows 8cl..8cl+7 = float4s 4cl..4cl+3, layout {W2[j][0],W2[j][1]} pairs
  float4 wA = ((const float4*)W2)[cl * 4 + 0];
  float4 wB = ((const float4*)W2)[cl * 4 + 1];
  float4 wC = ((const float4*)W2)[cl * 4 + 2];
  float4 wD = ((const float4*)W2)[cl * 4 + 3];
  float p0 = h0 * wA.x + h1 * wA.z + h2 * wB.x + h3 * wB.z
           + h4 * wC.x + h5 * wC.z + h6 * wD.x + h7 * wD.z;
  float p1 = h0 * wA.y + h1 * wA.w + h2 * wB.y + h3 * wB.w
           + h4 * wC.y + h5 * wC.w + h6 * wD.y + h7 * wD.w;
  for (int off = 1; off < 16; off <<= 1) {   // reduce the 16 channel groups
    p0 += __shfl_xor(p0, off);
    p1 += __shfl_xor(p1, off);
  }
  if (lane == 0) ((float2*)xs2)[d] = make_float2(p0 * dd, p1 * dd);
}

// ---------- gather2: out[d] = b2 + dinv[d]*(xs2[d] + sum xs2[src]) ----------
__global__ __launch_bounds__(256) void k_gather2(const int* __restrict__ wcnt,
                                                 const unsigned short* __restrict__ slot,
                                                 const float* __restrict__ xs2,
                                                 const float* __restrict__ dinv,
                                                 const float* __restrict__ b2,
                                                 float* __restrict__ out, int n) {
  int wave = threadIdx.x >> 6, lane = threadIdx.x & 63;
  int d = blockIdx.x * 4 + wave;
  if (d >= n) return;
  int cnt = wcnt[d];
  const unsigned short* slotd = slot + ((size_t)d << 7);
  float p0 = 0.f, p1 = 0.f;
  for (int k = lane; k < cnt; k += 64) {
    int s = slotd[k];
    float2 v = ((const float2*)xs2)[s];
    p0 += v.x; p1 += v.y;
  }
  for (int off = 32; off > 0; off >>= 1) {
    p0 += __shfl_down(p0, off);
    p1 += __shfl_down(p1, off);
  }
  if (lane == 0) {
    float dd = dinv[d];
    float2 self = ((const float2*)xs2)[d];
    out[d * 2 + 0] = fmaf(dd, p0 + self.x, b2[0]);
    out[d * 2 + 1] = fmaf(dd, p1 + self.y, b2[1]);
  }
}

extern "C" void kernel_launch(void* const* d_in, const int* in_sizes, int n_in,
                              void* d_out, int out_size, void* d_ws, size_t ws_size,
                              hipStream_t stream) {
  const float* x   = (const float*)d_in[0];
  const int*   ei  = (const int*)d_in[1];
  const float* g0  = (const float*)d_in[2];
  const float* be0 = (const float*)d_in[3];
  const float* m0  = (const float*)d_in[4];
  const float* v0  = (const float*)d_in[5];
  const float* W1  = (const float*)d_in[6];
  const float* b1  = (const float*)d_in[7];
  const float* g1  = (const float*)d_in[8];
  const float* be1 = (const float*)d_in[9];
  const float* m1  = (const float*)d_in[10];
  const float* v1  = (const float*)d_in[11];
  const float* W2  = (const float*)d_in[12];
  const float* b2  = (const float*)d_in[13];
  float* out = (float*)d_out;

  const int n = in_sizes[0] / 128;   // 50000 < 2^16: node ids fit in ushort (packed CSR)
  const int e = in_sizes[1] / 2;
  const int* esrc = ei;
  const int* edst = ei + e;
  const int npad = ((n + 63) / 64) * 64;

  // workspace layout (16B-aligned; n=50000) — ~53 MB.  gcur+cntp contiguous: one memset.
  int*            gcur   = (int*)d_ws;                             // 6272 ints
  int*            cntp   = gcur + 6272;                            // n*CS ints (6.4 MB, padded)
  unsigned int*   coarse = (unsigned int*)(cntp + (size_t)n * CS); // NB*CB uint (7.2 MB)
  unsigned short* slot   = (unsigned short*)(coarse + (size_t)NB * CB);  // n*CAP ushort (12.8 MB)
  int*            wcnt   = (int*)(slot + (size_t)n * CAP);         // n
  float*          dinv   = (float*)(wcnt + n);                     // n
  unsigned short* Wb     = (unsigned short*)(dinv + n);            // 16384 bf16 (32 KB)
  float*          c1     = (float*)(Wb + 16384);                   // 128
  float*          s1     = c1 + 128;                               // 128
  float*          u1     = s1 + 128;                               // 128
  float*          xs2    = u1 + 128;                               // n*2
  unsigned short* Xb     = (unsigned short*)(xs2 + (size_t)n * 2); // npad*128 bf16 (12.8 MB)
  unsigned short* xsb    = Xb + (size_t)npad * 128;                // (n+1)*128 bf16 (12.8 MB)

  const int nb_p1 = (e + CHUNK - 1) / CHUNK;       // 391
  const int cvb   = (npad * 32 + 255) / 256;       // cvtx blocks
  hipMemsetAsync(gcur, 0, (6272 + (size_t)n * CS) * sizeof(int), stream);
  k_A<<<nb_p1 + 1 + cvb, 256, 0, stream>>>(esrc, edst, gcur, cntp, coarse, e, nb_p1,
                                           W1, b1, g0, be0, m0, v0, g1, be1, m1, v1,
                                           (const float4*)x, Wb, c1, s1, u1, xsb,
                                           (uint2*)Xb, n, n * 32, npad * 32);
  k_B<<<NB + npad / 64, 256, 0, stream>>>(gcur, cntp, coarse, slot, wcnt, dinv,
                                          Xb, Wb, c1, xsb, n);
  k_gather1<<<(n + 3) / 4, 256, 0, stream>>>(wcnt, slot, (const uint4*)xsb, dinv, s1, u1, W2, xs2, n);
  k_gather2<<<(n + 3) / 4, 256, 0, stream>>>(wcnt, slot, xs2, dinv, b2, out, n);
}

// Round 13
// 238.908 us; speedup vs baseline: 2.4737x; 1.0700x over previous
//
#include <hip/hip_runtime.h>

#define EPS 1e-5f
#define CAP 128           // slots per dst (deg ~ Poisson(32); P(>=128) ~ 1e-40)
#define DR  128           // dsts per coarse bucket
#define NB  391           // ceil(50000/128) coarse buckets
#define CB  4608          // pairs per coarse bucket (mean 4096, +8 sigma)
#define GS  16            // gcur padding: 16 ints = 64B line per bucket
#define CHUNK 4096        // edges per phase-1 work block

typedef __attribute__((ext_vector_type(8))) short bf16x8;
typedef __attribute__((ext_vector_type(4))) float f32x4;

// branchless RNE fp32->bf16 (identical to __float2bfloat16 for finite inputs; pure int ops)
__device__ __forceinline__ unsigned int f2bf(float f) {
  union { float f; unsigned int u; } v; v.f = f;
  return (v.u + 0x7fffu + ((v.u >> 16) & 1u)) >> 16;
}
__device__ __forceinline__ float bf2f_lo(unsigned int u) {
  union { unsigned int i; float f; } v; v.i = u << 16; return v.f;
}
__device__ __forceinline__ float bf2f_hi(unsigned int u) {
  union { unsigned int i; float f; } v; v.i = u & 0xffff0000u; return v.f;
}

// ================= Kernel A: p1 (blocks [0,nbp1)) | prep (block nbp1) | cvtx (rest) ==========
// gcur pre-zeroed via hipMemsetAsync. NO global degree atomics (R12 lesson: device-scope
// atomics write-through ~48B/op at the coherence point -> 78MB of WRITE; degrees instead come
// free from p2's LDS lcnt in kernel B).
__global__ __launch_bounds__(256) void k_A(
    const int* __restrict__ esrc, const int* __restrict__ edst,
    int* __restrict__ gcur, unsigned int* __restrict__ coarse, int e, int nb_p1,
    const float* __restrict__ W1, const float* __restrict__ b1,
    const float* __restrict__ g0, const float* __restrict__ be0,
    const float* __restrict__ m0, const float* __restrict__ v0,
    const float* __restrict__ g1, const float* __restrict__ be1,
    const float* __restrict__ m1, const float* __restrict__ v1,
    const float4* __restrict__ x,
    unsigned short* __restrict__ Wb, float* __restrict__ c1,
    float* __restrict__ s1, float* __restrict__ u1,
    unsigned short* __restrict__ xsb,
    uint2* __restrict__ Xb4, int n, int n4, int npad4) {
  __shared__ int hist[NB];
  __shared__ int base[NB];
  __shared__ int loff[NB];
  __shared__ float s0s[128], t0s[128];
  const int tid = threadIdx.x;
  int bid = blockIdx.x;
  if (bid < nb_p1) {
    // ---- p1: coarse-bin edges, packed 4B entries ((d&127)<<16 | src); src < 2^16 ----
    for (int i = tid; i < NB; i += 256) { hist[i] = 0; loff[i] = 0; }
    __syncthreads();
    int e0 = bid * CHUNK;
    int e1 = min(e0 + CHUNK, e);
    for (int i = e0 + tid; i < e1; i += 256)
      atomicAdd(&hist[edst[i] >> 7], 1);
    __syncthreads();
    int rot = bid % NB;     // rotate reservation order: avoid cursor-line lockstep
    for (int bb = tid; bb < NB; bb += 256) {
      int b = bb + rot; if (b >= NB) b -= NB;
      int h = hist[b];
      if (h > 0) base[b] = atomicAdd(&gcur[b * GS], h);
    }
    __syncthreads();
    for (int i = e0 + tid; i < e1; i += 256) {
      int d = edst[i], s = esrc[i];
      int b = d >> 7;
      int p = base[b] + atomicAdd(&loff[b], 1);
      if (p < CB) coarse[(size_t)b * CB + p] = ((unsigned int)(d & 127) << 16) | (unsigned int)s;
    }
    return;
  }
  if (bid == nb_p1) {
    // ---- prep: BN folds, swizzled bf16 Wb, c1/s1/u1, zero xsb pad row ----
    if (tid < 128) {
      float s0 = g0[tid] * rsqrtf(v0[tid] + EPS);
      s0s[tid] = s0;
      t0s[tid] = be0[tid] - m0[tid] * s0;
      float s = g1[tid] * rsqrtf(v1[tid] + EPS);
      s1[tid] = s;
      u1[tid] = fmaf(b1[tid] - m1[tid], s, be1[tid]);  // h = relu(agg*s1 + u1)
    }
    __syncthreads();
    if (tid < 128) {
      float acc = 0.f;
      for (int k = 0; k < 128; ++k) acc = fmaf(t0s[k], W1[k * 128 + tid], acc);
      c1[tid] = acc;
    }
    if (tid < 16) ((uint4*)xsb)[(size_t)n * 16 + tid] = make_uint4(0, 0, 0, 0);  // pad row
    // Wb[((c*8+t)*64 + l)*8 + j] = bf16(s0[k]*W1[k][col]); k=c*32+(l>>4)*8+j, col=t*16+(l&15)
    for (int idx = tid; idx < 16384; idx += 256) {
      int k = idx >> 7, col = idx & 127;
      float w = W1[idx] * s0s[k];
      int c = k >> 5, j = k & 7, lq2 = (k >> 3) & 3;
      int t = col >> 4, li = col & 15;
      Wb[(((c * 8 + t) * 64) + lq2 * 16 + li) * 8 + j] = (unsigned short)f2bf(w);
    }
    return;
  }
  // ---- cvtx: Xb = bf16(x), rows >= n zero (pad to npad) ----
  int i = (bid - nb_p1 - 1) * 256 + tid;
  if (i >= npad4) return;
  uint2 o = make_uint2(0u, 0u);
  if (i < n4) {
    float4 v = x[i];
    o.x = (f2bf(v.y) << 16) | f2bf(v.x);
    o.y = (f2bf(v.w) << 16) | f2bf(v.z);
  }
  Xb4[i] = o;
}

// ================= Kernel B: one block per coarse bucket = p2 + GEMM for its own 128 rows ====
// After fine-binning, this block's row degrees sit in LDS (lcnt) -> xsb written PRE-SCALED
// with zero global counter traffic and zero extra dispatches. NB*128 = npad covers all rows.
__global__ __launch_bounds__(256, 4) void k_B(
    const int* __restrict__ gcur, const unsigned int* __restrict__ coarse,
    unsigned short* __restrict__ slot, int* __restrict__ wcnt, float* __restrict__ dinv,
    const unsigned short* __restrict__ Xb, const unsigned short* __restrict__ Wb,
    const float* __restrict__ c1, unsigned short* __restrict__ xsb, int n) {
  __shared__ int lcnt[DR];
  __shared__ int nqr[DR];
  __shared__ unsigned short lslot[DR * CAP];   // 32 KB
  const int tid = threadIdx.x;
  const int cb = blockIdx.x;
  const int dbase = cb * DR;
  // ---- p2: LDS fine-bin this coarse bucket ----
  for (int i = tid; i < DR; i += 256) lcnt[i] = 0;
  unsigned int padpat = ((unsigned int)n << 16) | (unsigned int)n;
  for (int q = tid; q < DR * CAP / 2; q += 256) ((unsigned int*)lslot)[q] = padpat;
  __syncthreads();
  int cnt = gcur[cb * GS]; if (cnt > CB) cnt = CB;
  const unsigned int* src = coarse + (size_t)cb * CB;
  for (int i = tid; i < cnt; i += 256) {
    unsigned int v = src[i];
    int ld = (int)(v >> 16);
    int pos = atomicAdd(&lcnt[ld], 1);
    if (pos < CAP) lslot[ld * CAP + pos] = (unsigned short)(v & 0xffffu);
  }
  __syncthreads();
  for (int ld = tid; ld < DR; ld += 256) {
    int c = min(lcnt[ld], CAP);
    nqr[ld] = ((((c + 3) >> 2) + 3) & ~3);   // quads rounded to x4 for the 4-deep gather
    int d = dbase + ld;
    if (d < n) {
      wcnt[d] = c;
      dinv[d] = rsqrtf((float)c + 1.0f);
    }
  }
  __syncthreads();
  const uint2* ls8 = (const uint2*)lslot;    // 8 B = one quad of 4 ushort slots
  uint2* s8 = (uint2*)slot;
  for (int idx = tid; idx < DR * 32; idx += 256) {
    int ld = idx >> 5, qi = idx & 31;
    if (qi < nqr[ld] && dbase + ld < n) s8[(size_t)cb * (DR * 32) + idx] = ls8[idx];
  }
  // ---- gemm (MFMA bf16, no LDS-staging): xsb rows dbase..dbase+127 = bf16((Xb@W + c1)*dinv) ----
  // dinv from LDS lcnt. A[m=lane&15][k=(lane>>4)*8+j]; D: col=lane&15, row=(lane>>4)*4+reg.
  const int wave = tid >> 6, lane = tid & 63;
  const int lr = lane & 15, lq = lane >> 4;
  const bf16x8* wb = (const bf16x8*)Wb;
  for (int t8 = wave; t8 < 8; t8 += 4) {     // 8 row-tiles of 16; 2 per wave
    int r0 = dbase + t8 * 16;
    const bf16x8* a_base = (const bf16x8*)(Xb + (size_t)(r0 + lr) * 128);  // 16 units/row
    f32x4 acc[8];
#pragma unroll
    for (int t = 0; t < 8; ++t) acc[t] = (f32x4){0.f, 0.f, 0.f, 0.f};
#pragma unroll
    for (int c = 0; c < 4; ++c) {
      bf16x8 a = a_base[c * 4 + lq];
#pragma unroll
      for (int t = 0; t < 8; ++t) {
        bf16x8 b = wb[(c * 8 + t) * 64 + lane];
        acc[t] = __builtin_amdgcn_mfma_f32_16x16x32_bf16(a, b, acc[t], 0, 0, 0);
      }
    }
#pragma unroll
    for (int reg = 0; reg < 4; ++reg) {
      int row = r0 + lq * 4 + reg;
      if (row < n) {
        float dd = rsqrtf((float)min(lcnt[row - dbase], CAP) + 1.0f);
        unsigned short* orow = xsb + (size_t)row * 128 + lr;
#pragma unroll
        for (int t = 0; t < 8; ++t) {
          float v = (acc[t][reg] + c1[t * 16 + lr]) * dd;
          orow[t * 16] = (unsigned short)f2bf(v);
        }
      }
    }
  }
}

// ---------- gather1 fused BN1+ReLU+GEMM2 (R9 body): wave per dst, 4 quad-loads in flight ----
// xsb rows pre-scaled by dinv[src]; lane = 16*sub + cl.
__global__ __launch_bounds__(256) void k_gather1(const int* __restrict__ wcnt,
                                                 const unsigned short* __restrict__ slot,
                                                 const uint4* __restrict__ xs4,
                                                 const float* __restrict__ dinv,
                                                 const float* __restrict__ s1,
                                                 const float* __restrict__ u1,
                                                 const float* __restrict__ W2,
                                                 float* __restrict__ xs2, int n) {
  int wave = threadIdx.x >> 6, lane = threadIdx.x & 63;
  int d = blockIdx.x * 4 + wave;
  if (d >= n) return;
  int sub = lane >> 4, cl = lane & 15;
  int cnt = wcnt[d];
  int nq4 = ((((cnt + 3) >> 2) + 3) & ~3);  // matches k_B rounding; pads -> zero row
  const unsigned short* slotd = slot + ((size_t)d << 7);
  float a0 = 0.f, a1 = 0.f, a2 = 0.f, a3 = 0.f, a4 = 0.f, a5 = 0.f, a6 = 0.f, a7 = 0.f;
#define ACC(R) { a0 += bf2f_lo(R.x); a1 += bf2f_hi(R.x); a2 += bf2f_lo(R.y); a3 += bf2f_hi(R.y); \
                 a4 += bf2f_lo(R.z); a5 += bf2f_hi(R.z); a6 += bf2f_lo(R.w); a7 += bf2f_hi(R.w); }
  for (int q = 0; q < nq4; q += 4) {        // 4 quad-loads (4KB) in flight, no tail
    int i0 = slotd[(q + 0) * 4 + sub];
    int i1 = slotd[(q + 1) * 4 + sub];
    int i2 = slotd[(q + 2) * 4 + sub];
    int i3 = slotd[(q + 3) * 4 + sub];
    uint4 r0 = xs4[(size_t)i0 * 16 + cl];
    uint4 r1 = xs4[(size_t)i1 * 16 + cl];
    uint4 r2 = xs4[(size_t)i2 * 16 + cl];
    uint4 r3 = xs4[(size_t)i3 * 16 + cl];
    ACC(r0); ACC(r1); ACC(r2); ACC(r3);
  }
  // fold the 4 edge-subgroups (xor 16, 32) -> every lane holds full channel sums
#define FOLD(OFF) { a0 += __shfl_xor(a0, OFF); a1 += __shfl_xor(a1, OFF); \
                    a2 += __shfl_xor(a2, OFF); a3 += __shfl_xor(a3, OFF); \
                    a4 += __shfl_xor(a4, OFF); a5 += __shfl_xor(a5, OFF); \
                    a6 += __shfl_xor(a6, OFF); a7 += __shfl_xor(a7, OFF); }
  FOLD(16); FOLD(32);
  uint4 sr = xs4[(size_t)d * 16 + cl];  // self-loop row (pre-scaled), added once after fold
  ACC(sr);
#undef ACC
#undef FOLD
  float dd = dinv[d];
  float4 sA = ((const float4*)s1)[cl * 2], sB = ((const float4*)s1)[cl * 2 + 1];
  float4 uA = ((const float4*)u1)[cl * 2], uB = ((const float4*)u1)[cl * 2 + 1];
  float h0 = fmaxf(fmaf(a0 * dd, sA.x, uA.x), 0.f);
  float h1 = fmaxf(fmaf(a1 * dd, sA.y, uA.y), 0.f);
  float h2 = fmaxf(fmaf(a2 * dd, sA.z, uA.z), 0.f);
  float h3 = fmaxf(fmaf(a3 * dd, sA.w, uA.w), 0.f);
  float h4 = fmaxf(fmaf(a4 * dd, sB.x, uB.x), 0.f);
  float h5 = fmaxf(fmaf(a5 * dd, sB.y, uB.y), 0.f);
  float h6 = fmaxf(fmaf(a6 * dd, sB.z, uB.z), 0.f);
  float h7 = fmaxf(fmaf(a7 * dd, sB.w, uB.w), 0.f);
  // W2 rows 8cl..8cl+7 = float4s 4cl..4cl+3, layout {W2[j][0],W2[j][1]} pairs
  float4 wA = ((const float4*)W2)[cl * 4 + 0];
  float4 wB = ((const float4*)W2)[cl * 4 + 1];
  float4 wC = ((const float4*)W2)[cl * 4 + 2];
  float4 wD = ((const float4*)W2)[cl * 4 + 3];
  float p0 = h0 * wA.x + h1 * wA.z + h2 * wB.x + h3 * wB.z
           + h4 * wC.x + h5 * wC.z + h6 * wD.x + h7 * wD.z;
  float p1 = h0 * wA.y + h1 * wA.w + h2 * wB.y + h3 * wB.w
           + h4 * wC.y + h5 * wC.w + h6 * wD.y + h7 * wD.w;
  for (int off = 1; off < 16; off <<= 1) {   // reduce the 16 channel groups
    p0 += __shfl_xor(p0, off);
    p1 += __shfl_xor(p1, off);
  }
  if (lane == 0) ((float2*)xs2)[d] = make_float2(p0 * dd, p1 * dd);
}

// ---------- gather2: out[d] = b2 + dinv[d]*(xs2[d] + sum xs2[src]) ----------
__global__ __launch_bounds__(256) void k_gather2(const int* __restrict__ wcnt,
                                                 const unsigned short* __restrict__ slot,
                                                 const float* __restrict__ xs2,
                                                 const float* __restrict__ dinv,
                                                 const float* __restrict__ b2,
                                                 float* __restrict__ out, int n) {
  int wave = threadIdx.x >> 6, lane = threadIdx.x & 63;
  int d = blockIdx.x * 4 + wave;
  if (d >= n) return;
  int cnt = wcnt[d];
  const unsigned short* slotd = slot + ((size_t)d << 7);
  float p0 = 0.f, p1 = 0.f;
  for (int k = lane; k < cnt; k += 64) {
    int s = slotd[k];
    float2 v = ((const float2*)xs2)[s];
    p0 += v.x; p1 += v.y;
  }
  for (int off = 32; off > 0; off >>= 1) {
    p0 += __shfl_down(p0, off);
    p1 += __shfl_down(p1, off);
  }
  if (lane == 0) {
    float dd = dinv[d];
    float2 self = ((const float2*)xs2)[d];
    out[d * 2 + 0] = fmaf(dd, p0 + self.x, b2[0]);
    out[d * 2 + 1] = fmaf(dd, p1 + self.y, b2[1]);
  }
}

extern "C" void kernel_launch(void* const* d_in, const int* in_sizes, int n_in,
                              void* d_out, int out_size, void* d_ws, size_t ws_size,
                              hipStream_t stream) {
  const float* x   = (const float*)d_in[0];
  const int*   ei  = (const int*)d_in[1];
  const float* g0  = (const float*)d_in[2];
  const float* be0 = (const float*)d_in[3];
  const float* m0  = (const float*)d_in[4];
  const float* v0  = (const float*)d_in[5];
  const float* W1  = (const float*)d_in[6];
  const float* b1  = (const float*)d_in[7];
  const float* g1  = (const float*)d_in[8];
  const float* be1 = (const float*)d_in[9];
  const float* m1  = (const float*)d_in[10];
  const float* v1  = (const float*)d_in[11];
  const float* W2  = (const float*)d_in[12];
  const float* b2  = (const float*)d_in[13];
  float* out = (float*)d_out;

  const int n = in_sizes[0] / 128;   // 50000 < 2^16: node ids fit in ushort (packed CSR)
  const int e = in_sizes[1] / 2;
  const int* esrc = ei;
  const int* edst = ei + e;
  const int npad = NB * DR;          // 50048; k_B covers exactly these rows

  // workspace layout (16B-aligned; n=50000) — ~46.5 MB
  int*            gcur   = (int*)d_ws;                             // 6272 ints
  unsigned int*   coarse = (unsigned int*)(gcur + 6272);           // NB*CB uint (7.2 MB)
  unsigned short* slot   = (unsigned short*)(coarse + (size_t)NB * CB);  // n*CAP ushort (12.8 MB)
  int*            wcnt   = (int*)(slot + (size_t)n * CAP);         // n
  float*          dinv   = (float*)(wcnt + n);                     // n
  unsigned short* Wb     = (unsigned short*)(dinv + n);            // 16384 bf16 (32 KB)
  float*          c1     = (float*)(Wb + 16384);                   // 128
  float*          s1     = c1 + 128;                               // 128
  float*          u1     = s1 + 128;                               // 128
  float*          xs2    = u1 + 128;                               // n*2
  unsigned short* Xb     = (unsigned short*)(xs2 + (size_t)n * 2); // npad*128 bf16 (12.8 MB)
  unsigned short* xsb    = Xb + (size_t)npad * 128;                // (n+1)*128 bf16 (12.8 MB)

  const int nb_p1 = (e + CHUNK - 1) / CHUNK;       // 391
  const int cvb   = (npad * 32 + 255) / 256;       // cvtx blocks
  hipMemsetAsync(gcur, 0, 6272 * sizeof(int), stream);
  k_A<<<nb_p1 + 1 + cvb, 256, 0, stream>>>(esrc, edst, gcur, coarse, e, nb_p1,
                                           W1, b1, g0, be0, m0, v0, g1, be1, m1, v1,
                                           (const float4*)x, Wb, c1, s1, u1, xsb,
                                           (uint2*)Xb, n, n * 32, npad * 32);
  k_B<<<NB, 256, 0, stream>>>(gcur, coarse, slot, wcnt, dinv, Xb, Wb, c1, xsb, n);
  k_gather1<<<(n + 3) / 4, 256, 0, stream>>>(wcnt, slot, (const uint4*)xsb, dinv, s1, u1, W2, xs2, n);
  k_gather2<<<(n + 3) / 4, 256, 0, stream>>>(wcnt, slot, xs2, dinv, b2, out, n);
}

// Round 14
// 213.884 us; speedup vs baseline: 2.7631x; 1.1170x over previous
//
#include <hip/hip_runtime.h>

#define EPS 1e-5f
#define CAP 128           // slots per dst (deg ~ Poisson(32); P(>=128) ~ 1e-40)
#define DR  64            // dsts per coarse bucket (halved: 782 k_B blocks -> ~3/CU)
#define NBB 782           // ceil(50000/64) coarse buckets
#define NP  391           // cursor PAIRS; each pair shares one 64B line (16 ints)
#define CB  2432          // pairs per coarse bucket (mean 2046, +8.5 sigma)
#define CHUNK 4096        // edges per p1 block

typedef __attribute__((ext_vector_type(8))) short bf16x8;
typedef __attribute__((ext_vector_type(4))) float f32x4;

// branchless RNE fp32->bf16 (identical to __float2bfloat16 for finite inputs; pure int ops)
__device__ __forceinline__ unsigned int f2bf(float f) {
  union { float f; unsigned int u; } v; v.f = f;
  return (v.u + 0x7fffu + ((v.u >> 16) & 1u)) >> 16;
}
__device__ __forceinline__ float bf2f_lo(unsigned int u) {
  union { unsigned int i; float f; } v; v.i = u << 16; return v.f;
}
__device__ __forceinline__ float bf2f_hi(unsigned int u) {
  union { unsigned int i; float f; } v; v.i = u & 0xffff0000u; return v.f;
}

// ================= Kernel A: p1 (blocks [0,nbp1)) | prep (block nbp1) | cvtx (rest) ==========
// p1 is SINGLE-PASS over the edge list: (d<<16)|src packed into 16 regs during histogram.
// Cursor reservations use one 64-bit atomicAdd per bucket PAIR (both bases in the return).
__global__ __launch_bounds__(256) void k_A(
    const int* __restrict__ esrc, const int* __restrict__ edst,
    int* __restrict__ gcur, unsigned int* __restrict__ coarse, int e, int nb_p1,
    const float* __restrict__ W1, const float* __restrict__ b1,
    const float* __restrict__ g0, const float* __restrict__ be0,
    const float* __restrict__ m0, const float* __restrict__ v0,
    const float* __restrict__ g1, const float* __restrict__ be1,
    const float* __restrict__ m1, const float* __restrict__ v1,
    const float4* __restrict__ x,
    unsigned short* __restrict__ Wb, float* __restrict__ c1,
    float* __restrict__ s1, float* __restrict__ u1,
    unsigned short* __restrict__ xsb,
    uint2* __restrict__ Xb4, int n, int n4, int npad4) {
  __shared__ int hist[NBB];
  __shared__ int base[NBB];
  __shared__ int loff[NBB];
  __shared__ float s0s[128], t0s[128];
  const int tid = threadIdx.x;
  int bid = blockIdx.x;
  if (bid < nb_p1) {
    for (int i = tid; i < NBB; i += 256) { hist[i] = 0; loff[i] = 0; }
    __syncthreads();
    int e0 = bid * CHUNK;
    unsigned int pk[16];                       // packed edges: (d<<16)|src, sentinel ~0
#pragma unroll
    for (int j = 0; j < 16; ++j) {
      int i = e0 + tid + j * 256;
      unsigned int v = 0xffffffffu;
      if (i < e) {
        int d = edst[i], s = esrc[i];
        v = ((unsigned int)d << 16) | (unsigned int)s;
        atomicAdd(&hist[d >> 6], 1);
      }
      pk[j] = v;
    }
    __syncthreads();
    int rot = bid % NP;                        // de-lockstep reservation order
    for (int pp = tid; pp < NP; pp += 256) {
      int p = pp + rot; if (p >= NP) p -= NP;
      unsigned int h0 = (unsigned int)hist[2 * p], h1 = (unsigned int)hist[2 * p + 1];
      if (h0 | h1) {
        unsigned long long old = atomicAdd((unsigned long long*)&gcur[p * 16],
                                           ((unsigned long long)h1 << 32) | h0);
        base[2 * p]     = (int)(old & 0xffffffffu);
        base[2 * p + 1] = (int)(old >> 32);
      }
    }
    __syncthreads();
#pragma unroll
    for (int j = 0; j < 16; ++j) {
      unsigned int v = pk[j];
      if (v != 0xffffffffu) {
        int b = v >> 22;                       // d >> 6
        int p = base[b] + atomicAdd(&loff[b], 1);
        if (p < CB) coarse[(size_t)b * CB + p] = v & 0x003fffffu;  // (d&63)<<16 | src
      }
    }
    return;
  }
  if (bid == nb_p1) {
    // ---- prep: BN folds, swizzled bf16 Wb, c1/s1/u1, zero xsb pad row ----
    if (tid < 128) {
      float s0 = g0[tid] * rsqrtf(v0[tid] + EPS);
      s0s[tid] = s0;
      t0s[tid] = be0[tid] - m0[tid] * s0;
      float s = g1[tid] * rsqrtf(v1[tid] + EPS);
      s1[tid] = s;
      u1[tid] = fmaf(b1[tid] - m1[tid], s, be1[tid]);  // h = relu(agg*s1 + u1)
    }
    __syncthreads();
    if (tid < 128) {
      float acc = 0.f;
      for (int k = 0; k < 128; ++k) acc = fmaf(t0s[k], W1[k * 128 + tid], acc);
      c1[tid] = acc;
    }
    if (tid < 16) ((uint4*)xsb)[(size_t)n * 16 + tid] = make_uint4(0, 0, 0, 0);  // pad row
    // Wb[((c*8+t)*64 + l)*8 + j] = bf16(s0[k]*W1[k][col]); k=c*32+(l>>4)*8+j, col=t*16+(l&15)
    for (int idx = tid; idx < 16384; idx += 256) {
      int k = idx >> 7, col = idx & 127;
      float w = W1[idx] * s0s[k];
      int c = k >> 5, j = k & 7, lq2 = (k >> 3) & 3;
      int t = col >> 4, li = col & 15;
      Wb[(((c * 8 + t) * 64) + lq2 * 16 + li) * 8 + j] = (unsigned short)f2bf(w);
    }
    return;
  }
  // ---- cvtx: Xb = bf16(x), rows >= n zero (pad to npad) ----
  int i = (bid - nb_p1 - 1) * 256 + tid;
  if (i >= npad4) return;
  uint2 o = make_uint2(0u, 0u);
  if (i < n4) {
    float4 v = x[i];
    o.x = (f2bf(v.y) << 16) | f2bf(v.x);
    o.y = (f2bf(v.w) << 16) | f2bf(v.z);
  }
  Xb4[i] = o;
}

// ================= Kernel B: one block per coarse bucket = p2 + GEMM for its own 64 rows ====
// Degrees from LDS lcnt -> xsb written PRE-SCALED, zero global counter traffic.
// DR=64: 782 blocks (~3/CU), 16KB LDS tile, one 16-row MFMA tile per wave.
__global__ __launch_bounds__(256, 4) void k_B(
    const int* __restrict__ gcur, const unsigned int* __restrict__ coarse,
    unsigned short* __restrict__ slot, int* __restrict__ wcnt, float* __restrict__ dinv,
    const unsigned short* __restrict__ Xb, const unsigned short* __restrict__ Wb,
    const float* __restrict__ c1, unsigned short* __restrict__ xsb, int n) {
  __shared__ int lcnt[DR];
  __shared__ int nqr[DR];
  __shared__ unsigned short lslot[DR * CAP];   // 16 KB
  const int tid = threadIdx.x;
  const int cb = blockIdx.x;
  const int dbase = cb * DR;
  for (int i = tid; i < DR; i += 256) lcnt[i] = 0;
  unsigned int padpat = ((unsigned int)n << 16) | (unsigned int)n;
  for (int q = tid; q < DR * CAP / 2; q += 256) ((unsigned int*)lslot)[q] = padpat;
  __syncthreads();
  int cnt = gcur[(cb >> 1) * 16 + (cb & 1)]; if (cnt > CB) cnt = CB;
  const unsigned int* src = coarse + (size_t)cb * CB;
  for (int i = tid; i < cnt; i += 256) {
    unsigned int v = src[i];
    int ld = (int)(v >> 16);                   // 6 bits
    int pos = atomicAdd(&lcnt[ld], 1);
    if (pos < CAP) lslot[ld * CAP + pos] = (unsigned short)(v & 0xffffu);
  }
  __syncthreads();
  for (int ld = tid; ld < DR; ld += 256) {
    int c = min(lcnt[ld], CAP);
    nqr[ld] = ((((c + 3) >> 2) + 3) & ~3);     // quads rounded to x4 for the 4-deep gather
    int d = dbase + ld;
    if (d < n) {
      wcnt[d] = c;
      dinv[d] = rsqrtf((float)c + 1.0f);
    }
  }
  __syncthreads();
  const uint2* ls8 = (const uint2*)lslot;      // 8 B = one quad of 4 ushort slots
  uint2* s8 = (uint2*)slot;
  for (int idx = tid; idx < DR * 32; idx += 256) {
    int ld = idx >> 5, qi = idx & 31;
    if (qi < nqr[ld] && dbase + ld < n) s8[(size_t)dbase * 32 + idx] = ls8[idx];
  }
  // ---- gemm (MFMA bf16): rows dbase..dbase+63 = bf16((Xb@W + c1) * rsqrt(lcnt+1)) ----
  // A[m=lane&15][k=(lane>>4)*8+j]; D: col=lane&15, row=(lane>>4)*4+reg (verified layouts).
  const int wave = tid >> 6, lane = tid & 63;
  const int lr = lane & 15, lq = lane >> 4;
  const bf16x8* wb = (const bf16x8*)Wb;
  int r0 = dbase + wave * 16;                  // 4 waves cover all 64 rows
  const bf16x8* a_base = (const bf16x8*)(Xb + (size_t)(r0 + lr) * 128);  // 16 units/row
  f32x4 acc[8];
#pragma unroll
  for (int t = 0; t < 8; ++t) acc[t] = (f32x4){0.f, 0.f, 0.f, 0.f};
#pragma unroll
  for (int c = 0; c < 4; ++c) {
    bf16x8 a = a_base[c * 4 + lq];
#pragma unroll
    for (int t = 0; t < 8; ++t) {
      bf16x8 b = wb[(c * 8 + t) * 64 + lane];
      acc[t] = __builtin_amdgcn_mfma_f32_16x16x32_bf16(a, b, acc[t], 0, 0, 0);
    }
  }
#pragma unroll
  for (int reg = 0; reg < 4; ++reg) {
    int row = r0 + lq * 4 + reg;
    if (row < n) {
      float dd = rsqrtf((float)min(lcnt[row - dbase], CAP) + 1.0f);
      unsigned short* orow = xsb + (size_t)row * 128 + lr;
#pragma unroll
      for (int t = 0; t < 8; ++t) {
        float v = (acc[t][reg] + c1[t * 16 + lr]) * dd;
        orow[t * 16] = (unsigned short)f2bf(v);
      }
    }
  }
}

// ---------- gather1 fused BN1+ReLU+GEMM2 (R9 body): wave per dst, 4 quad-loads in flight ----
// xsb rows pre-scaled by dinv[src]; lane = 16*sub + cl.
__global__ __launch_bounds__(256) void k_gather1(const int* __restrict__ wcnt,
                                                 const unsigned short* __restrict__ slot,
                                                 const uint4* __restrict__ xs4,
                                                 const float* __restrict__ dinv,
                                                 const float* __restrict__ s1,
                                                 const float* __restrict__ u1,
                                                 const float* __restrict__ W2,
                                                 float* __restrict__ xs2, int n) {
  int wave = threadIdx.x >> 6, lane = threadIdx.x & 63;
  int d = blockIdx.x * 4 + wave;
  if (d >= n) return;
  int sub = lane >> 4, cl = lane & 15;
  int cnt = wcnt[d];
  int nq4 = ((((cnt + 3) >> 2) + 3) & ~3);  // matches k_B rounding; pads -> zero row
  const unsigned short* slotd = slot + ((size_t)d << 7);
  float a0 = 0.f, a1 = 0.f, a2 = 0.f, a3 = 0.f, a4 = 0.f, a5 = 0.f, a6 = 0.f, a7 = 0.f;
#define ACC(R) { a0 += bf2f_lo(R.x); a1 += bf2f_hi(R.x); a2 += bf2f_lo(R.y); a3 += bf2f_hi(R.y); \
                 a4 += bf2f_lo(R.z); a5 += bf2f_hi(R.z); a6 += bf2f_lo(R.w); a7 += bf2f_hi(R.w); }
  for (int q = 0; q < nq4; q += 4) {        // 4 quad-loads (4KB) in flight, no tail
    int i0 = slotd[(q + 0) * 4 + sub];
    int i1 = slotd[(q + 1) * 4 + sub];
    int i2 = slotd[(q + 2) * 4 + sub];
    int i3 = slotd[(q + 3) * 4 + sub];
    uint4 r0 = xs4[(size_t)i0 * 16 + cl];
    uint4 r1 = xs4[(size_t)i1 * 16 + cl];
    uint4 r2 = xs4[(size_t)i2 * 16 + cl];
    uint4 r3 = xs4[(size_t)i3 * 16 + cl];
    ACC(r0); ACC(r1); ACC(r2); ACC(r3);
  }
  // fold the 4 edge-subgroups (xor 16, 32) -> every lane holds full channel sums
#define FOLD(OFF) { a0 += __shfl_xor(a0, OFF); a1 += __shfl_xor(a1, OFF); \
                    a2 += __shfl_xor(a2, OFF); a3 += __shfl_xor(a3, OFF); \
                    a4 += __shfl_xor(a4, OFF); a5 += __shfl_xor(a5, OFF); \
                    a6 += __shfl_xor(a6, OFF); a7 += __shfl_xor(a7, OFF); }
  FOLD(16); FOLD(32);
  uint4 sr = xs4[(size_t)d * 16 + cl];  // self-loop row (pre-scaled), added once after fold
  ACC(sr);
#undef ACC
#undef FOLD
  float dd = dinv[d];
  float4 sA = ((const float4*)s1)[cl * 2], sB = ((const float4*)s1)[cl * 2 + 1];
  float4 uA = ((const float4*)u1)[cl * 2], uB = ((const float4*)u1)[cl * 2 + 1];
  float h0 = fmaxf(fmaf(a0 * dd, sA.x, uA.x), 0.f);
  float h1 = fmaxf(fmaf(a1 * dd, sA.y, uA.y), 0.f);
  float h2 = fmaxf(fmaf(a2 * dd, sA.z, uA.z), 0.f);
  float h3 = fmaxf(fmaf(a3 * dd, sA.w, uA.w), 0.f);
  float h4 = fmaxf(fmaf(a4 * dd, sB.x, uB.x), 0.f);
  float h5 = fmaxf(fmaf(a5 * dd, sB.y, uB.y), 0.f);
  float h6 = fmaxf(fmaf(a6 * dd, sB.z, uB.z), 0.f);
  float h7 = fmaxf(fmaf(a7 * dd, sB.w, uB.w), 0.f);
  // W2 rows 8cl..8cl+7 = float4s 4cl..4cl+3, layout {W2[j][0],W2[j][1]} pairs
  float4 wA = ((const float4*)W2)[cl * 4 + 0];
  float4 wB = ((const float4*)W2)[cl * 4 + 1];
  float4 wC = ((const float4*)W2)[cl * 4 + 2];
  float4 wD = ((const float4*)W2)[cl * 4 + 3];
  float p0 = h0 * wA.x + h1 * wA.z + h2 * wB.x + h3 * wB.z
           + h4 * wC.x + h5 * wC.z + h6 * wD.x + h7 * wD.z;
  float p1 = h0 * wA.y + h1 * wA.w + h2 * wB.y + h3 * wB.w
           + h4 * wC.y + h5 * wC.w + h6 * wD.y + h7 * wD.w;
  for (int off = 1; off < 16; off <<= 1) {   // reduce the 16 channel groups
    p0 += __shfl_xor(p0, off);
    p1 += __shfl_xor(p1, off);
  }
  if (lane == 0) ((float2*)xs2)[d] = make_float2(p0 * dd, p1 * dd);
}

// ---------- gather2: out[d] = b2 + dinv[d]*(xs2[d] + sum xs2[src]) ----------
__global__ __launch_bounds__(256) void k_gather2(const int* __restrict__ wcnt,
                                                 const unsigned short* __restrict__ slot,
                                                 const float* __restrict__ xs2,
                                                 const float* __restrict__ dinv,
                                                 const float* __restrict__ b2,
                                                 float* __restrict__ out, int n) {
  int wave = threadIdx.x >> 6, lane = threadIdx.x & 63;
  int d = blockIdx.x * 4 + wave;
  if (d >= n) return;
  int cnt = wcnt[d];
  const unsigned short* slotd = slot + ((size_t)d << 7);
  float p0 = 0.f, p1 = 0.f;
  for (int k = lane; k < cnt; k += 64) {
    int s = slotd[k];
    float2 v = ((const float2*)xs2)[s];
    p0 += v.x; p1 += v.y;
  }
  for (int off = 32; off > 0; off >>= 1) {
    p0 += __shfl_down(p0, off);
    p1 += __shfl_down(p1, off);
  }
  if (lane == 0) {
    float dd = dinv[d];
    float2 self = ((const float2*)xs2)[d];
    out[d * 2 + 0] = fmaf(dd, p0 + self.x, b2[0]);
    out[d * 2 + 1] = fmaf(dd, p1 + self.y, b2[1]);
  }
}

extern "C" void kernel_launch(void* const* d_in, const int* in_sizes, int n_in,
                              void* d_out, int out_size, void* d_ws, size_t ws_size,
                              hipStream_t stream) {
  const float* x   = (const float*)d_in[0];
  const int*   ei  = (const int*)d_in[1];
  const float* g0  = (const float*)d_in[2];
  const float* be0 = (const float*)d_in[3];
  const float* m0  = (const float*)d_in[4];
  const float* v0  = (const float*)d_in[5];
  const float* W1  = (const float*)d_in[6];
  const float* b1  = (const float*)d_in[7];
  const float* g1  = (const float*)d_in[8];
  const float* be1 = (const float*)d_in[9];
  const float* m1  = (const float*)d_in[10];
  const float* v1  = (const float*)d_in[11];
  const float* W2  = (const float*)d_in[12];
  const float* b2  = (const float*)d_in[13];
  float* out = (float*)d_out;

  const int n = in_sizes[0] / 128;   // 50000 < 2^16: node ids fit in ushort (packed CSR)
  const int e = in_sizes[1] / 2;
  const int* esrc = ei;
  const int* edst = ei + e;
  const int npad = NBB * DR;         // 50048; k_B covers exactly these rows

  // workspace layout (16B-aligned; n=50000) — ~47 MB
  int*            gcur   = (int*)d_ws;                             // NP*16 ints (25 KB)
  unsigned int*   coarse = (unsigned int*)(gcur + NP * 16);        // NBB*CB uint (7.6 MB)
  unsigned short* slot   = (unsigned short*)(coarse + (size_t)NBB * CB); // n*CAP ushort (12.8 MB)
  int*            wcnt   = (int*)(slot + (size_t)n * CAP);         // n
  float*          dinv   = (float*)(wcnt + n);                     // n
  unsigned short* Wb     = (unsigned short*)(dinv + n);            // 16384 bf16 (32 KB)
  float*          c1     = (float*)(Wb + 16384);                   // 128
  float*          s1     = c1 + 128;                               // 128
  float*          u1     = s1 + 128;                               // 128
  float*          xs2    = u1 + 128;                               // n*2
  unsigned short* Xb     = (unsigned short*)(xs2 + (size_t)n * 2); // npad*128 bf16 (12.8 MB)
  unsigned short* xsb    = Xb + (size_t)npad * 128;                // (n+1)*128 bf16 (12.8 MB)

  const int nb_p1 = (e + CHUNK - 1) / CHUNK;       // 391
  const int cvb   = (npad * 32 + 255) / 256;       // cvtx blocks
  hipMemsetAsync(gcur, 0, NP * 16 * sizeof(int), stream);
  k_A<<<nb_p1 + 1 + cvb, 256, 0, stream>>>(esrc, edst, gcur, coarse, e, nb_p1,
                                           W1, b1, g0, be0, m0, v0, g1, be1, m1, v1,
                                           (const float4*)x, Wb, c1, s1, u1, xsb,
                                           (uint2*)Xb, n, n * 32, npad * 32);
  k_B<<<NBB, 256, 0, stream>>>(gcur, coarse, slot, wcnt, dinv, Xb, Wb, c1, xsb, n);
  k_gather1<<<(n + 3) / 4, 256, 0, stream>>>(wcnt, slot, (const uint4*)xsb, dinv, s1, u1, W2, xs2, n);
  k_gather2<<<(n + 3) / 4, 256, 0, stream>>>(wcnt, slot, xs2, dinv, b2, out, n);
}